// Round 2
// baseline (33.389 us; speedup 1.0000x reference)
//
#include <hip/hip_runtime.h>
#include <algorithm>
#include <cstdint>

// ---------------------------------------------------------------------------
// Host-side reproduction of jax.random.permutation(jax.random.key(42), 128)
// under jax_threefry_partitionable=True (default since JAX 0.4.36):
//   key = threefry_seed(42) = (0, 42)
//   split: counts = iota_2x32_shape((2,)) -> hi=[0,0], lo=[0,1]
//          subkey = threefry_block(key, x0=0, x1=1)  (both output words)
//   random_bits(subkey, 32, (128,)): per i, block(subkey, x0=0, x1=i),
//          bits[i] = x0_out ^ x1_out
//   perm = stable argsort(bits); use perm[0:25]
// (Legacy non-partitionable path — tried round 0 — FAILED on this harness.)
// ---------------------------------------------------------------------------

static inline void threefry2x32_block(uint32_t k0, uint32_t k1,
                                      uint32_t& x0, uint32_t& x1) {
  auto rotl = [](uint32_t v, int d) { return (v << d) | (v >> (32 - d)); };
  const int r0[4] = {13, 15, 26, 6};
  const int r1[4] = {17, 29, 16, 24};
  const uint32_t ks0 = k0, ks1 = k1, ks2 = k0 ^ k1 ^ 0x1BD11BDAu;
  x0 += ks0; x1 += ks1;
  for (int i = 0; i < 4; ++i) { x0 += x1; x1 = rotl(x1, r0[i]); x1 ^= x0; }
  x0 += ks1; x1 += ks2 + 1u;
  for (int i = 0; i < 4; ++i) { x0 += x1; x1 = rotl(x1, r1[i]); x1 ^= x0; }
  x0 += ks2; x1 += ks0 + 2u;
  for (int i = 0; i < 4; ++i) { x0 += x1; x1 = rotl(x1, r0[i]); x1 ^= x0; }
  x0 += ks0; x1 += ks1 + 3u;
  for (int i = 0; i < 4; ++i) { x0 += x1; x1 = rotl(x1, r1[i]); x1 ^= x0; }
  x0 += ks1; x1 += ks2 + 4u;
  for (int i = 0; i < 4; ++i) { x0 += x1; x1 = rotl(x1, r0[i]); x1 ^= x0; }
  x0 += ks2; x1 += ks0 + 5u;
}

struct Perm25 { int p[25]; };

static Perm25 compute_perm25() {
  // subkey via fold-like split: block over 64-bit iota element 1 -> (hi=0, lo=1)
  uint32_t sk0 = 0u, sk1 = 1u;
  threefry2x32_block(0u, 42u, sk0, sk1);

  // partitionable random_bits(subkey, 32, (128,)): bits[i] = x0out ^ x1out
  // of block(subkey, x0=iota_hi=0, x1=iota_lo=i).
  uint32_t bits[128];
  for (int i = 0; i < 128; ++i) {
    uint32_t x0 = 0u, x1 = (uint32_t)i;
    threefry2x32_block(sk0, sk1, x0, x1);
    bits[i] = x0 ^ x1;
  }

  int idxs[128];
  for (int i = 0; i < 128; ++i) idxs[i] = i;
  std::stable_sort(idxs, idxs + 128,
                   [&](int a, int b) { return bits[a] < bits[b]; });

  Perm25 out;
  for (int j = 0; j < 25; ++j) out.p[j] = idxs[j];
  return out;
}

// ---------------------------------------------------------------------------
// Kernel: out[b*25+j] = adj_info[ids[b]*128 + perm[j]]; duplicated into the
// second output (adj_sampled == weights_sampled in the reference).
// ---------------------------------------------------------------------------

#define NS 25
#define MAX_DEG 128

__global__ __launch_bounds__(256)
void uniform_sampler_kernel(const int* __restrict__ adj,
                            const int* __restrict__ ids,
                            int* __restrict__ out,
                            Perm25 perm, int batch) {
  const int idx = blockIdx.x * blockDim.x + threadIdx.x;
  const int total = batch * NS;
  if (idx >= total) return;
  const unsigned b = (unsigned)idx / NS;        // magic-mul division
  const int j = idx - (int)b * NS;
  const int node = ids[b];
  const int v = adj[(size_t)node * MAX_DEG + perm.p[j]];
  out[idx] = v;           // adj_sampled
  out[total + idx] = v;   // weights_sampled (identical)
}

extern "C" void kernel_launch(void* const* d_in, const int* in_sizes, int n_in,
                              void* d_out, int out_size, void* d_ws, size_t ws_size,
                              hipStream_t stream) {
  const int* adj = (const int*)d_in[0];   // (100000, 128) int32
  const int* ids = (const int*)d_in[1];   // (262144,)    int32
  // d_in[2] = num_samples (25), fixed by the reference; NS hard-coded.

  const int batch = in_sizes[1];
  const int total = batch * NS;           // per-output element count

  const Perm25 perm = compute_perm25();   // pure host arithmetic, deterministic

  const int block = 256;
  const int grid = (total + block - 1) / block;
  uniform_sampler_kernel<<<grid, block, 0, stream>>>(adj, ids, (int*)d_out,
                                                     perm, batch);
}

// Round 3
// 32.084 us; speedup vs baseline: 1.0407x; 1.0407x over previous
//
#include <hip/hip_runtime.h>
#include <algorithm>
#include <cstdint>

// ---------------------------------------------------------------------------
// Host-side reproduction of jax.random.permutation(jax.random.key(42), 128)
// under jax_threefry_partitionable=True (default since JAX 0.4.36):
//   key = threefry_seed(42) = (0, 42)
//   split: subkey = threefry_block(key, x0=0, x1=1) (both output words)
//   random_bits(subkey, 32, (128,)): bits[i] = x0out ^ x1out of
//          block(subkey, x0=0, x1=i)
//   perm = stable argsort(bits); use perm[0:25]
// (Verified passing on this harness, round 2.)
// ---------------------------------------------------------------------------

static inline void threefry2x32_block(uint32_t k0, uint32_t k1,
                                      uint32_t& x0, uint32_t& x1) {
  auto rotl = [](uint32_t v, int d) { return (v << d) | (v >> (32 - d)); };
  const int r0[4] = {13, 15, 26, 6};
  const int r1[4] = {17, 29, 16, 24};
  const uint32_t ks0 = k0, ks1 = k1, ks2 = k0 ^ k1 ^ 0x1BD11BDAu;
  x0 += ks0; x1 += ks1;
  for (int i = 0; i < 4; ++i) { x0 += x1; x1 = rotl(x1, r0[i]); x1 ^= x0; }
  x0 += ks1; x1 += ks2 + 1u;
  for (int i = 0; i < 4; ++i) { x0 += x1; x1 = rotl(x1, r1[i]); x1 ^= x0; }
  x0 += ks2; x1 += ks0 + 2u;
  for (int i = 0; i < 4; ++i) { x0 += x1; x1 = rotl(x1, r0[i]); x1 ^= x0; }
  x0 += ks0; x1 += ks1 + 3u;
  for (int i = 0; i < 4; ++i) { x0 += x1; x1 = rotl(x1, r1[i]); x1 ^= x0; }
  x0 += ks1; x1 += ks2 + 4u;
  for (int i = 0; i < 4; ++i) { x0 += x1; x1 = rotl(x1, r0[i]); x1 ^= x0; }
  x0 += ks2; x1 += ks0 + 5u;
}

struct Perm25 { int p[25]; };

static Perm25 compute_perm25() {
  uint32_t sk0 = 0u, sk1 = 1u;
  threefry2x32_block(0u, 42u, sk0, sk1);

  uint32_t bits[128];
  for (int i = 0; i < 128; ++i) {
    uint32_t x0 = 0u, x1 = (uint32_t)i;
    threefry2x32_block(sk0, sk1, x0, x1);
    bits[i] = x0 ^ x1;
  }

  int idxs[128];
  for (int i = 0; i < 128; ++i) idxs[i] = i;
  std::stable_sort(idxs, idxs + 128,
                   [&](int a, int b) { return bits[a] < bits[b]; });

  Perm25 out;
  for (int j = 0; j < 25; ++j) out.p[j] = idxs[j];
  return out;
}

// ---------------------------------------------------------------------------
// Kernel: per 256-thread block, stage 32 full adjacency rows (32 x 512 B)
// into LDS with coalesced int4 loads (25 random cols touch ~all 4 cache
// lines of a 512 B row anyway, so full-row reads cost the same traffic as
// the scattered gather but with ~16x fewer VMEM transactions), then gather
// the 25 permuted columns from LDS and store both outputs as coalesced int4.
// LDS row stride padded to 132 words so gather bank = (4r + perm[j]) % 32
// spreads same-j lanes across banks.
// ---------------------------------------------------------------------------

#define NS 25
#define MAX_DEG 128
#define ROWS_PER_BLOCK 32
#define LDS_STRIDE 132   // 128 + 4 pad; keeps 16B alignment (132*4 = 528 = 33*16)
#define ELEMS (ROWS_PER_BLOCK * NS)   // 800 outputs per block per output array

__global__ __launch_bounds__(256)
void uniform_sampler_kernel(const int* __restrict__ adj,
                            const int* __restrict__ ids,
                            int* __restrict__ out,
                            Perm25 perm, int batch) {
  __shared__ int s_rows[ROWS_PER_BLOCK * LDS_STRIDE];  // ~16.5 KB
  __shared__ int s_ids[ROWS_PER_BLOCK];
  __shared__ int s_perm[NS];

  const int tid = threadIdx.x;
  const int row0 = blockIdx.x * ROWS_PER_BLOCK;

  if (tid < ROWS_PER_BLOCK) {
    const int gr = row0 + tid;
    s_ids[tid] = (gr < batch) ? ids[gr] : 0;
  }
  if (tid < NS) s_perm[tid] = perm.p[tid];
  __syncthreads();

  // Phase 1: stage 32 rows, coalesced. 8 rows per iteration
  // (32 lanes x int4 = 512 B = one full row per 32 lanes).
#pragma unroll
  for (int it = 0; it < 4; ++it) {
    const int r = it * 8 + (tid >> 5);
    const int c = tid & 31;
    const int node = s_ids[r];
    const int4 v =
        *reinterpret_cast<const int4*>(adj + (size_t)node * MAX_DEG + c * 4);
    *reinterpret_cast<int4*>(&s_rows[r * LDS_STRIDE + c * 4]) = v;
  }
  __syncthreads();

  // Phase 2: 800 outputs = 200 int4 stores per output array.
  if (tid < ELEMS / 4) {
    int vals[4];
#pragma unroll
    for (int e = 0; e < 4; ++e) {
      const int li = tid * 4 + e;
      const unsigned r = (unsigned)li / NS;   // magic-mul div
      const int j = li - (int)r * NS;
      vals[e] = s_rows[r * LDS_STRIDE + s_perm[j]];
    }
    const int4 v = make_int4(vals[0], vals[1], vals[2], vals[3]);
    const size_t base = (size_t)blockIdx.x * ELEMS + (size_t)tid * 4;
    const size_t total = (size_t)batch * NS;
    if (base + 4 <= total) {
      *reinterpret_cast<int4*>(out + base) = v;           // adj_sampled
      *reinterpret_cast<int4*>(out + total + base) = v;   // weights_sampled
    }
  }
}

extern "C" void kernel_launch(void* const* d_in, const int* in_sizes, int n_in,
                              void* d_out, int out_size, void* d_ws, size_t ws_size,
                              hipStream_t stream) {
  const int* adj = (const int*)d_in[0];   // (100000, 128) int32
  const int* ids = (const int*)d_in[1];   // (262144,)    int32
  // d_in[2] = num_samples (25), fixed by the reference; NS hard-coded.

  const int batch = in_sizes[1];          // 262144 (divisible by 32)

  const Perm25 perm = compute_perm25();   // pure host arithmetic, deterministic

  const int grid = (batch + ROWS_PER_BLOCK - 1) / ROWS_PER_BLOCK;  // 8192
  uniform_sampler_kernel<<<grid, 256, 0, stream>>>(adj, ids, (int*)d_out,
                                                   perm, batch);
}

// Round 5
// 28.648 us; speedup vs baseline: 1.1655x; 1.1199x over previous
//
#include <hip/hip_runtime.h>
#include <algorithm>
#include <cstdint>

// ---------------------------------------------------------------------------
// Host-side reproduction of jax.random.permutation(jax.random.key(42), 128)
// under jax_threefry_partitionable=True (default since JAX 0.4.36):
//   subkey = threefry_block(key=(0,42), x0=0, x1=1) (both output words)
//   bits[i] = x0out ^ x1out of block(subkey, x0=0, x1=i), i in [0,128)
//   perm = stable argsort(bits); use perm[0:25]
// (Verified passing on this harness, rounds 2-3.)
// ---------------------------------------------------------------------------

static inline void threefry2x32_block(uint32_t k0, uint32_t k1,
                                      uint32_t& x0, uint32_t& x1) {
  auto rotl = [](uint32_t v, int d) { return (v << d) | (v >> (32 - d)); };
  const int r0[4] = {13, 15, 26, 6};
  const int r1[4] = {17, 29, 16, 24};
  const uint32_t ks0 = k0, ks1 = k1, ks2 = k0 ^ k1 ^ 0x1BD11BDAu;
  x0 += ks0; x1 += ks1;
  for (int i = 0; i < 4; ++i) { x0 += x1; x1 = rotl(x1, r0[i]); x1 ^= x0; }
  x0 += ks1; x1 += ks2 + 1u;
  for (int i = 0; i < 4; ++i) { x0 += x1; x1 = rotl(x1, r1[i]); x1 ^= x0; }
  x0 += ks2; x1 += ks0 + 2u;
  for (int i = 0; i < 4; ++i) { x0 += x1; x1 = rotl(x1, r0[i]); x1 ^= x0; }
  x0 += ks0; x1 += ks1 + 3u;
  for (int i = 0; i < 4; ++i) { x0 += x1; x1 = rotl(x1, r1[i]); x1 ^= x0; }
  x0 += ks1; x1 += ks2 + 4u;
  for (int i = 0; i < 4; ++i) { x0 += x1; x1 = rotl(x1, r0[i]); x1 ^= x0; }
  x0 += ks2; x1 += ks0 + 5u;
}

struct Perm25 { int p[25]; };

static Perm25 compute_perm25() {
  uint32_t sk0 = 0u, sk1 = 1u;
  threefry2x32_block(0u, 42u, sk0, sk1);
  uint32_t bits[128];
  for (int i = 0; i < 128; ++i) {
    uint32_t x0 = 0u, x1 = (uint32_t)i;
    threefry2x32_block(sk0, sk1, x0, x1);
    bits[i] = x0 ^ x1;
  }
  int idxs[128];
  for (int i = 0; i < 128; ++i) idxs[i] = i;
  std::stable_sort(idxs, idxs + 128,
                   [&](int a, int b) { return bits[a] < bits[b]; });
  Perm25 out;
  for (int j = 0; j < 25; ++j) out.p[j] = idxs[j];
  return out;
}

#define NS 25
#define MAX_DEG 128
#define ROWS_PER_BLOCK 32
#define LDS_STRIDE 132      // 128+4 pad; 132*4=528 B keeps int4 alignment
#define TMP_STRIDE 32       // compacted row padded to 128 B (aligned lines)
#define ELEMS (ROWS_PER_BLOCK * NS)  // 800 outputs/block/output-array

// clang native vector — __builtin_nontemporal_store requires this, not
// HIP's int4 class type.
typedef int iv4 __attribute__((ext_vector_type(4)));

// ---------------------------------------------------------------------------
// Kernel A: dedupe pass. Each adjacency row is read from HBM exactly ONCE
// (vs 2.62x average in the direct gather), its 25 permuted columns are
// compacted into tmp[node][0..24] (row padded to 128 B). 51.2 MB read +
// 12.8 MB write instead of 134 MB read.
// ---------------------------------------------------------------------------
__global__ __launch_bounds__(256)
void compact_rows_kernel(const int* __restrict__ adj,
                         int* __restrict__ tmp,
                         Perm25 perm, int n_nodes) {
  __shared__ int s_rows[ROWS_PER_BLOCK * LDS_STRIDE];  // ~16.5 KB
  __shared__ int s_perm[NS];

  const int tid = threadIdx.x;
  const int row0 = blockIdx.x * ROWS_PER_BLOCK;
  if (tid < NS) s_perm[tid] = perm.p[tid];
  __syncthreads();

  // Stage 32 full rows, coalesced (wave = 2 rows x 512 B).
#pragma unroll
  for (int it = 0; it < 4; ++it) {
    const int r = it * 8 + (tid >> 5);
    const int c = tid & 31;
    const int node = row0 + r;               // sequential: rows in order
    if (node < n_nodes) {
      const int4 v =
          *reinterpret_cast<const int4*>(adj + (size_t)node * MAX_DEG + c * 4);
      *reinterpret_cast<int4*>(&s_rows[r * LDS_STRIDE + c * 4]) = v;
    }
  }
  __syncthreads();

  // Gather 25 perm columns per row, pad to 32, write coalesced 128 B rows.
  // thread t: r = t>>3 (row), q = t&7 (int4 chunk of the 32-col tmp row).
  const int r = tid >> 3;
  const int q = tid & 7;
  const int node = row0 + r;
  if (node < n_nodes) {
    iv4 v;
#pragma unroll
    for (int e = 0; e < 4; ++e) {
      const int j = q * 4 + e;
      v[e] = (j < NS) ? s_rows[r * LDS_STRIDE + s_perm[j]] : 0;
    }
    *reinterpret_cast<iv4*>(tmp + (size_t)node * TMP_STRIDE + q * 4) = v;
  }
}

// ---------------------------------------------------------------------------
// Kernel B: per block stage 32 compacted rows tmp[ids[...]] (128 B each,
// single-line aligned reads, L2/IC-hot from kernel A), then write both
// outputs coalesced with non-temporal stores (outputs never re-read; keep
// L2 for tmp).
// ---------------------------------------------------------------------------
#define B_STRIDE 36   // 36*4=144 B: int4-aligned rows, banks rotate by 4/row

__global__ __launch_bounds__(256)
void scatter_out_kernel(const int* __restrict__ tmp,
                        const int* __restrict__ ids,
                        int* __restrict__ out, int batch) {
  __shared__ int s_tmp[ROWS_PER_BLOCK * B_STRIDE];  // 4.6 KB
  __shared__ int s_ids[ROWS_PER_BLOCK];

  const int tid = threadIdx.x;
  const int row0 = blockIdx.x * ROWS_PER_BLOCK;

  if (tid < ROWS_PER_BLOCK) {
    const int gr = row0 + tid;
    s_ids[tid] = (gr < batch) ? ids[gr] : 0;
  }
  __syncthreads();

  // Stage: thread t loads int4 chunk q=t&7 of row r=t>>3 (one 128 B line
  // per row, 8 lanes per line — fully coalesced within the line).
  {
    const int r = tid >> 3;
    const int q = tid & 7;
    const int node = s_ids[r];
    const int4 v = *reinterpret_cast<const int4*>(
        tmp + (size_t)node * TMP_STRIDE + q * 4);
    *reinterpret_cast<int4*>(&s_tmp[r * B_STRIDE + q * 4]) = v;
  }
  __syncthreads();

  // 800 outputs = 200 int4 NT stores per output array.
  if (tid < ELEMS / 4) {
    iv4 v;
#pragma unroll
    for (int e = 0; e < 4; ++e) {
      const int li = tid * 4 + e;
      const unsigned r = (unsigned)li / NS;   // magic-mul div
      const int j = li - (int)r * NS;
      v[e] = s_tmp[r * B_STRIDE + j];
    }
    const size_t base = (size_t)blockIdx.x * ELEMS + (size_t)tid * 4;
    const size_t total = (size_t)batch * NS;
    if (base + 4 <= total) {
      __builtin_nontemporal_store(v, reinterpret_cast<iv4*>(out + base));
      __builtin_nontemporal_store(v,
                                  reinterpret_cast<iv4*>(out + total + base));
    }
  }
}

// ---------------------------------------------------------------------------
// Fallback (round-2 verified): direct gather, used only if ws too small.
// ---------------------------------------------------------------------------
__global__ __launch_bounds__(256)
void direct_sampler_kernel(const int* __restrict__ adj,
                           const int* __restrict__ ids,
                           int* __restrict__ out,
                           Perm25 perm, int batch) {
  __shared__ int s_rows[ROWS_PER_BLOCK * LDS_STRIDE];
  __shared__ int s_ids[ROWS_PER_BLOCK];
  __shared__ int s_perm[NS];

  const int tid = threadIdx.x;
  const int row0 = blockIdx.x * ROWS_PER_BLOCK;
  if (tid < ROWS_PER_BLOCK) {
    const int gr = row0 + tid;
    s_ids[tid] = (gr < batch) ? ids[gr] : 0;
  }
  if (tid < NS) s_perm[tid] = perm.p[tid];
  __syncthreads();
#pragma unroll
  for (int it = 0; it < 4; ++it) {
    const int r = it * 8 + (tid >> 5);
    const int c = tid & 31;
    const int node = s_ids[r];
    const int4 v =
        *reinterpret_cast<const int4*>(adj + (size_t)node * MAX_DEG + c * 4);
    *reinterpret_cast<int4*>(&s_rows[r * LDS_STRIDE + c * 4]) = v;
  }
  __syncthreads();
  if (tid < ELEMS / 4) {
    iv4 v;
#pragma unroll
    for (int e = 0; e < 4; ++e) {
      const int li = tid * 4 + e;
      const unsigned r = (unsigned)li / NS;
      const int j = li - (int)r * NS;
      v[e] = s_rows[r * LDS_STRIDE + s_perm[j]];
    }
    const size_t base = (size_t)blockIdx.x * ELEMS + (size_t)tid * 4;
    const size_t total = (size_t)batch * NS;
    if (base + 4 <= total) {
      __builtin_nontemporal_store(v, reinterpret_cast<iv4*>(out + base));
      __builtin_nontemporal_store(v,
                                  reinterpret_cast<iv4*>(out + total + base));
    }
  }
}

extern "C" void kernel_launch(void* const* d_in, const int* in_sizes, int n_in,
                              void* d_out, int out_size, void* d_ws, size_t ws_size,
                              hipStream_t stream) {
  const int* adj = (const int*)d_in[0];   // (100000, 128) int32
  const int* ids = (const int*)d_in[1];   // (262144,)    int32

  const int n_nodes = in_sizes[0] / MAX_DEG;  // 100000
  const int batch = in_sizes[1];              // 262144

  const Perm25 perm = compute_perm25();       // host arithmetic, deterministic

  const size_t tmp_bytes = (size_t)n_nodes * TMP_STRIDE * sizeof(int);
  const int gridB = (batch + ROWS_PER_BLOCK - 1) / ROWS_PER_BLOCK;  // 8192

  if (ws_size >= tmp_bytes) {
    int* tmp = (int*)d_ws;
    const int gridA = (n_nodes + ROWS_PER_BLOCK - 1) / ROWS_PER_BLOCK;  // 3125
    compact_rows_kernel<<<gridA, 256, 0, stream>>>(adj, tmp, perm, n_nodes);
    scatter_out_kernel<<<gridB, 256, 0, stream>>>(tmp, ids, (int*)d_out, batch);
  } else {
    direct_sampler_kernel<<<gridB, 256, 0, stream>>>(adj, ids, (int*)d_out,
                                                     perm, batch);
  }
}